// Round 2
// baseline (529.251 us; speedup 1.0000x reference)
//
#include <hip/hip_runtime.h>
#include <math.h>

typedef float    float4_t __attribute__((ext_vector_type(4)));
typedef _Float16 half8    __attribute__((ext_vector_type(8)));
typedef _Float16 half4_t  __attribute__((ext_vector_type(4)));

// ---------------- Kernel P: fused h-GEMM + s1/s2 + hT(fp16) ------------------
__global__ __launch_bounds__(256) void k_prep(const float* __restrict__ inp,
                                              const float* __restrict__ W,
                                              const float* __restrict__ a,
                                              float* __restrict__ s1,
                                              float* __restrict__ s2,
                                              _Float16* __restrict__ hT) {
    __shared__ float sA[32 * 68];
    __shared__ float sW[64 * 128];
    const int t   = threadIdx.x;
    const int gr0 = blockIdx.x * 32;          // global row base (0..16383)
    const int b   = gr0 >> 12;                // batch
    const int f0  = (t & 15) * 8;
    const int r0  = (t >> 4) * 2;
    float4_t acc0[2] = {}; float4_t acc1[2] = {};
    for (int kc = 0; kc < 4; ++kc) {
        __syncthreads();
        #pragma unroll
        for (int it = 0; it < 2; ++it) {      // stage inp 32x64
            int fi = it * 256 + t; int r = fi >> 4; int c = (fi & 15) * 4;
            *(float4_t*)&sA[r * 68 + c] =
                *(const float4_t*)&inp[(size_t)(gr0 + r) * 256 + kc * 64 + c];
        }
        #pragma unroll
        for (int it = 0; it < 8; ++it) {      // stage W 64x128
            int fi = it * 256 + t; int k = fi >> 5; int c = (fi & 31) * 4;
            *(float4_t*)&sW[k * 128 + c] =
                *(const float4_t*)&W[(size_t)(kc * 64 + k) * 128 + c];
        }
        __syncthreads();
        for (int k = 0; k < 64; ++k) {
            float4_t w0 = *(const float4_t*)&sW[k * 128 + f0];
            float4_t w1 = *(const float4_t*)&sW[k * 128 + f0 + 4];
            #pragma unroll
            for (int r = 0; r < 2; ++r) {
                float av = sA[(r0 + r) * 68 + k];
                acc0[r] += av * w0; acc1[r] += av * w1;
            }
        }
    }
    float4_t a1lo = *(const float4_t*)&a[f0];
    float4_t a1hi = *(const float4_t*)&a[f0 + 4];
    float4_t a2lo = *(const float4_t*)&a[128 + f0];
    float4_t a2hi = *(const float4_t*)&a[128 + f0 + 4];
    #pragma unroll
    for (int r = 0; r < 2; ++r) {
        const int row  = gr0 + r0 + r;
        const int rloc = row & 4095;
        #pragma unroll
        for (int c = 0; c < 4; ++c) {
            hT[(size_t)b * (128 * 4096) + (size_t)(f0 + c) * 4096 + rloc]     = (_Float16)acc0[r][c];
            hT[(size_t)b * (128 * 4096) + (size_t)(f0 + 4 + c) * 4096 + rloc] = (_Float16)acc1[r][c];
        }
        float p1 = acc0[r][0]*a1lo[0] + acc0[r][1]*a1lo[1] + acc0[r][2]*a1lo[2] + acc0[r][3]*a1lo[3]
                 + acc1[r][0]*a1hi[0] + acc1[r][1]*a1hi[1] + acc1[r][2]*a1hi[2] + acc1[r][3]*a1hi[3];
        float p2 = acc0[r][0]*a2lo[0] + acc0[r][1]*a2lo[1] + acc0[r][2]*a2lo[2] + acc0[r][3]*a2lo[3]
                 + acc1[r][0]*a2hi[0] + acc1[r][1]*a2hi[1] + acc1[r][2]*a2hi[2] + acc1[r][3]*a2hi[3];
        #pragma unroll
        for (int o = 1; o < 16; o <<= 1) { p1 += __shfl_xor(p1, o); p2 += __shfl_xor(p2, o); }
        if ((t & 15) == 0) { s1[row] = p1; s2[row] = p2; }
    }
}

// ---------------- Kernel M: per-batch s2 max ---------------------------------
__global__ __launch_bounds__(256) void k_s2max(const float* __restrict__ s2,
                                               float* __restrict__ s2max) {
    const int b = blockIdx.x, t = threadIdx.x;
    float m = -INFINITY;
    for (int i = t; i < 4096; i += 256) m = fmaxf(m, s2[b * 4096 + i]);
    #pragma unroll
    for (int o = 1; o < 64; o <<= 1) m = fmaxf(m, __shfl_xor(m, o));
    __shared__ float sm[4];
    if ((t & 63) == 0) sm[t >> 6] = m;
    __syncthreads();
    if (t == 0) s2max[b] = fmaxf(fmaxf(sm[0], sm[1]), fmaxf(sm[2], sm[3]));
}

// ---------------- Kernel F: fixed-max attention + P@H ------------------------
// Grid 1024 x 256 (4 j-splits x 64 row-blocks x 4 batches). Wave = 16 rows.
// Round-0 verified LDS structure (hbuf dbuf xor-swizzled, wave-private pbuf,
// one barrier/tile) + NEW: adj/s2 software-pipelined TWO tiles deep in
// ping-ponged register sets (avA/avB), hand-unrolled x2 so every register
// index is compile-time static. adj consumed at jt is refilled for jt+2
// immediately after the exp phase, so ~900cyc HBM latency hides under
// ~2 full iterations of MFMA/LDS/VALU work instead of being exposed.
__global__ __launch_bounds__(256, 4) void k_flash(const float* __restrict__ adj,
                                                  const _Float16* __restrict__ hT,
                                                  const float* __restrict__ s1,
                                                  const float* __restrict__ s2,
                                                  const float* __restrict__ s2max,
                                                  float* __restrict__ part_acc,
                                                  float* __restrict__ part_l) {
    __shared__ _Float16 hbuf[2][128 * 64];    // 32 KB, hT dbuf, xor-swizzled
    __shared__ _Float16 pbuf[4][16 * 64];     // 8 KB, wave-private p tiles

    const int t    = threadIdx.x;
    const int bid  = blockIdx.x;
    const int sp   = bid & 3;                 // j-split
    const int rb   = (bid >> 2) & 63;         // 64-row block within batch
    const int b    = bid >> 8;                // batch
    const int w    = t >> 6, lane = t & 63;
    const int quad = lane >> 4, ln15 = lane & 15;
    const int g    = quad;                    // row-group for p-compute
    const int cl   = ln15;                    // col-lane for p-compute
    const int rowb = rb * 64 + w * 16;        // wave's 16-row base
    const float*    adj_w = adj + (size_t)b * 4096 * 4096 + (size_t)rowb * 4096;
    const _Float16* hT_b  = hT + (size_t)b * 128 * 4096;
    const float*    s2_b  = s2 + b * 4096;
    const float     s2m   = s2max[b];
    const int jwbase = sp * 1024;

    float s1r[4], mh[4];
    #pragma unroll
    for (int L = 0; L < 4; ++L) {
        s1r[L] = s1[b * 4096 + rowb + L * 4 + g];
        mh[L]  = fmaxf(0.f, s1r[L] + s2m);
    }

    // hT staging geometry: thread covers f-rows i*32+(t>>3), j-chunk t&7
    const int sf  = t >> 3;
    const int sc  = t & 7;
    const int fb7 = ln15 & 7;

    float4_t acc[8] = {};
    float4_t psacc = {0.f, 0.f, 0.f, 0.f};

    // ---- preload hT tile 0 into hbuf[0] ----
    {
        half8 hreg[4];
        #pragma unroll
        for (int i = 0; i < 4; ++i) {
            int f = i * 32 + sf;
            hreg[i] = *(const half8*)&hT_b[(size_t)f * 4096 + jwbase + sc * 8];
        }
        #pragma unroll
        for (int i = 0; i < 4; ++i) {
            int f = i * 32 + sf;
            *(half8*)&hbuf[0][f * 64 + ((sc ^ (f & 7)) << 3)] = hreg[i];
        }
    }

    // ---- prologue: adj/s2 for jt=0 (A set) and jt=1 (B set) ----
    float4_t avA[4], avB[4];
    float4_t s2vA, s2vB;
    #pragma unroll
    for (int L = 0; L < 4; ++L) {
        avA[L] = *(const float4_t*)&adj_w[(size_t)(L * 4 + g) * 4096 + jwbase + cl * 4];
        avB[L] = *(const float4_t*)&adj_w[(size_t)(L * 4 + g) * 4096 + jwbase + 64 + cl * 4];
    }
    s2vA = *(const float4_t*)&s2_b[jwbase + cl * 4];
    s2vB = *(const float4_t*)&s2_b[jwbase + 64 + cl * 4];

    __syncthreads();

    // one flash iteration; av/s2v consumed then refilled for jt+2 (if pfA)
    auto body = [&](int jt, int cur, float4_t (&av)[4], float4_t& s2v, bool pfA) {
        const int j0 = jwbase + jt * 64;
        // prefetch hT tile jt+1 into regs (consumed after MFMA)
        half8 hreg[4];
        const bool pfH = (jt < 15);
        if (pfH) {
            #pragma unroll
            for (int i = 0; i < 4; ++i) {
                int f = i * 32 + sf;
                hreg[i] = *(const half8*)&hT_b[(size_t)f * 4096 + j0 + 64 + sc * 8];
            }
        }
        // ---- p = exp(adj*leaky(s1+s2) - mhat), write to wave-private pbuf ----
        #pragma unroll
        for (int L = 0; L < 4; ++L) {
            half4_t qv;
            #pragma unroll
            for (int c = 0; c < 4; ++c) {
                float x = s1r[L] + s2v[c];
                float e = x > 0.f ? x : 0.2f * x;
                float p = av[L][c] > 0.f ? __expf(fmaf(av[L][c], e, -mh[L])) : 0.f;
                _Float16 q = (_Float16)p;
                qv[c] = q;
                psacc[L] += (float)q;
            }
            const int r     = L * 4 + g;
            const int c0    = cl * 4;
            const int chunk = (c0 >> 3) ^ (r & 7);
            *(half4_t*)&pbuf[w][r * 64 + chunk * 8 + (c0 & 7)] = qv;
        }
        // ---- refill av/s2v for jt+2 (2-deep pipeline; regs just consumed) ----
        if (pfA) {
            #pragma unroll
            for (int L = 0; L < 4; ++L)
                av[L] = *(const float4_t*)&adj_w[(size_t)(L * 4 + g) * 4096 + j0 + 128 + cl * 4];
            s2v = *(const float4_t*)&s2_b[j0 + 128 + cl * 4];
        }
        // wave-private pbuf: writes visible to this wave's reads after lgkmcnt(0)
        asm volatile("s_waitcnt lgkmcnt(0)" ::: "memory");
        // ---- A-frags from pbuf, B-frags from hbuf[cur], MFMA ----
        half8 afrag[2];
        #pragma unroll
        for (int kc = 0; kc < 2; ++kc) {
            const int chunk = ((kc << 2) + quad) ^ (ln15 & 7);
            afrag[kc] = *(const half8*)&pbuf[w][ln15 * 64 + chunk * 8];
        }
        #pragma unroll
        for (int nt = 0; nt < 8; ++nt) {
            #pragma unroll
            for (int kc = 0; kc < 2; ++kc) {
                const int fb = nt * 16 + ln15;
                half8 bfrag = *(const half8*)&hbuf[cur][fb * 64 + ((((kc << 2) + quad) ^ fb7) << 3)];
                acc[nt] = __builtin_amdgcn_mfma_f32_16x16x32_f16(afrag[kc], bfrag, acc[nt], 0, 0, 0);
            }
        }
        // ---- commit hT jt+1 to other buffer ----
        if (pfH) {
            #pragma unroll
            for (int i = 0; i < 4; ++i) {
                int f = i * 32 + sf;
                *(half8*)&hbuf[cur ^ 1][f * 64 + ((sc ^ (f & 7)) << 3)] = hreg[i];
            }
        }
        __syncthreads();
    };

    #pragma unroll 1
    for (int jt2 = 0; jt2 < 8; ++jt2) {
        body(2 * jt2,     0, avA, s2vA, jt2 < 7);
        body(2 * jt2 + 1, 1, avB, s2vB, jt2 < 7);
    }

    // ---- epilogue: reduce l within each 16-lane group, write partials ----
    #pragma unroll
    for (int o = 1; o < 16; o <<= 1) {
        #pragma unroll
        for (int L = 0; L < 4; ++L) psacc[L] += __shfl_xor(psacc[L], o);
    }
    const size_t growb = (size_t)b * 4096 + rowb;
    if (cl == 0) {
        #pragma unroll
        for (int L = 0; L < 4; ++L)
            part_l[(size_t)sp * 16384 + growb + L * 4 + g] = psacc[L];
    }
    float* pacc = part_acc + (size_t)sp * 16384 * 128;
    #pragma unroll
    for (int nt = 0; nt < 8; ++nt) {
        #pragma unroll
        for (int reg = 0; reg < 4; ++reg) {
            pacc[(growb + quad * 4 + reg) * 128 + nt * 16 + ln15] = acc[nt][reg];
        }
    }
}

// ---------------- Kernel E: sum 4 j-split partials, normalize, elu -----------
__global__ __launch_bounds__(256) void k_combine(const float* __restrict__ part_acc,
                                                 const float* __restrict__ part_l,
                                                 float* __restrict__ out) {
    const int idx = blockIdx.x * 256 + threadIdx.x;   // 0..524287
    const int e0  = idx * 4;
    const int gr  = e0 >> 7;
    float l = part_l[gr] + part_l[16384 + gr] + part_l[32768 + gr] + part_l[49152 + gr];
    float4_t a0 = *(const float4_t*)&part_acc[e0];
    float4_t a1 = *(const float4_t*)&part_acc[2097152 + e0];
    float4_t a2 = *(const float4_t*)&part_acc[4194304 + e0];
    float4_t a3 = *(const float4_t*)&part_acc[6291456 + e0];
    float4_t s  = (a0 + a1) + (a2 + a3);
    float rl = 1.f / l;
    float4_t o;
    #pragma unroll
    for (int c = 0; c < 4; ++c) {
        float v = s[c] * rl;
        o[c] = v > 0.f ? v : expm1f(v);
    }
    *(float4_t*)&((float*)out)[e0] = o;
}

extern "C" void kernel_launch(void* const* d_in, const int* in_sizes, int n_in,
                              void* d_out, int out_size, void* d_ws, size_t ws_size,
                              hipStream_t stream) {
    const float* inp = (const float*)d_in[0];   // (4,4096,256)
    const float* adj = (const float*)d_in[1];   // (4,4096,4096)
    const float* W   = (const float*)d_in[2];   // (256,128)
    const float* a   = (const float*)d_in[3];   // (256,1)
    float* out = (float*)d_out;                 // (4,4096,128)

    char* wsb = (char*)d_ws;
    _Float16* hT       = (_Float16*)(wsb);                // 4 MB
    float*    s1       = (float*)(wsb + 4194304);         // 64 KB
    float*    s2       = (float*)(wsb + 4259840);         // 64 KB
    float*    s2max    = (float*)(wsb + 4325376);         // 256 B
    float*    part_l   = (float*)(wsb + 4325632);         // 256 KB
    float*    part_acc = (float*)(wsb + 4587776);         // 32 MB (total ~36.4 MB)

    hipLaunchKernelGGL(k_prep,    dim3(512),  dim3(256), 0, stream, inp, W, a, s1, s2, hT);
    hipLaunchKernelGGL(k_s2max,   dim3(4),    dim3(256), 0, stream, s2, s2max);
    hipLaunchKernelGGL(k_flash,   dim3(1024), dim3(256), 0, stream, adj, hT, s1, s2, s2max,
                       part_acc, part_l);
    hipLaunchKernelGGL(k_combine, dim3(2048), dim3(256), 0, stream, part_acc, part_l, out);
}

// Round 3
// 446.368 us; speedup vs baseline: 1.1857x; 1.1857x over previous
//
#include <hip/hip_runtime.h>
#include <math.h>

typedef float    float4_t __attribute__((ext_vector_type(4)));
typedef _Float16 half8    __attribute__((ext_vector_type(8)));
typedef _Float16 half4_t  __attribute__((ext_vector_type(4)));

// ---------------- Kernel P: fused h-GEMM + s1/s2 + hT(fp16) ------------------
__global__ __launch_bounds__(256) void k_prep(const float* __restrict__ inp,
                                              const float* __restrict__ W,
                                              const float* __restrict__ a,
                                              float* __restrict__ s1,
                                              float* __restrict__ s2,
                                              _Float16* __restrict__ hT) {
    __shared__ float sA[32 * 68];
    __shared__ float sW[64 * 128];
    const int t   = threadIdx.x;
    const int gr0 = blockIdx.x * 32;          // global row base (0..16383)
    const int b   = gr0 >> 12;                // batch
    const int f0  = (t & 15) * 8;
    const int r0  = (t >> 4) * 2;
    float4_t acc0[2] = {}; float4_t acc1[2] = {};
    for (int kc = 0; kc < 4; ++kc) {
        __syncthreads();
        #pragma unroll
        for (int it = 0; it < 2; ++it) {      // stage inp 32x64
            int fi = it * 256 + t; int r = fi >> 4; int c = (fi & 15) * 4;
            *(float4_t*)&sA[r * 68 + c] =
                *(const float4_t*)&inp[(size_t)(gr0 + r) * 256 + kc * 64 + c];
        }
        #pragma unroll
        for (int it = 0; it < 8; ++it) {      // stage W 64x128
            int fi = it * 256 + t; int k = fi >> 5; int c = (fi & 31) * 4;
            *(float4_t*)&sW[k * 128 + c] =
                *(const float4_t*)&W[(size_t)(kc * 64 + k) * 128 + c];
        }
        __syncthreads();
        for (int k = 0; k < 64; ++k) {
            float4_t w0 = *(const float4_t*)&sW[k * 128 + f0];
            float4_t w1 = *(const float4_t*)&sW[k * 128 + f0 + 4];
            #pragma unroll
            for (int r = 0; r < 2; ++r) {
                float av = sA[(r0 + r) * 68 + k];
                acc0[r] += av * w0; acc1[r] += av * w1;
            }
        }
    }
    float4_t a1lo = *(const float4_t*)&a[f0];
    float4_t a1hi = *(const float4_t*)&a[f0 + 4];
    float4_t a2lo = *(const float4_t*)&a[128 + f0];
    float4_t a2hi = *(const float4_t*)&a[128 + f0 + 4];
    #pragma unroll
    for (int r = 0; r < 2; ++r) {
        const int row  = gr0 + r0 + r;
        const int rloc = row & 4095;
        #pragma unroll
        for (int c = 0; c < 4; ++c) {
            hT[(size_t)b * (128 * 4096) + (size_t)(f0 + c) * 4096 + rloc]     = (_Float16)acc0[r][c];
            hT[(size_t)b * (128 * 4096) + (size_t)(f0 + 4 + c) * 4096 + rloc] = (_Float16)acc1[r][c];
        }
        float p1 = acc0[r][0]*a1lo[0] + acc0[r][1]*a1lo[1] + acc0[r][2]*a1lo[2] + acc0[r][3]*a1lo[3]
                 + acc1[r][0]*a1hi[0] + acc1[r][1]*a1hi[1] + acc1[r][2]*a1hi[2] + acc1[r][3]*a1hi[3];
        float p2 = acc0[r][0]*a2lo[0] + acc0[r][1]*a2lo[1] + acc0[r][2]*a2lo[2] + acc0[r][3]*a2lo[3]
                 + acc1[r][0]*a2hi[0] + acc1[r][1]*a2hi[1] + acc1[r][2]*a2hi[2] + acc1[r][3]*a2hi[3];
        #pragma unroll
        for (int o = 1; o < 16; o <<= 1) { p1 += __shfl_xor(p1, o); p2 += __shfl_xor(p2, o); }
        if ((t & 15) == 0) { s1[row] = p1; s2[row] = p2; }
    }
}

// ---------------- Kernel M: per-batch s2 max ---------------------------------
__global__ __launch_bounds__(256) void k_s2max(const float* __restrict__ s2,
                                               float* __restrict__ s2max) {
    const int b = blockIdx.x, t = threadIdx.x;
    float m = -INFINITY;
    for (int i = t; i < 4096; i += 256) m = fmaxf(m, s2[b * 4096 + i]);
    #pragma unroll
    for (int o = 1; o < 64; o <<= 1) m = fmaxf(m, __shfl_xor(m, o));
    __shared__ float sm[4];
    if ((t & 63) == 0) sm[t >> 6] = m;
    __syncthreads();
    if (t == 0) s2max[b] = fmaxf(fmaxf(sm[0], sm[1]), fmaxf(sm[2], sm[3]));
}

// ---------------- Kernel F: fixed-max attention + P@H ------------------------
// Grid 1024 x 256 (4 j-splits x 64 row-blocks x 4 batches). Wave = 16 rows.
// Round-0 data layout (hbuf dbuf xor-swizzle, wave-private pbuf) + NEW:
//  (a) RAW barrier: asm lgkmcnt(0) + __builtin_amdgcn_s_barrier(), NOT
//      __syncthreads() -- so adj VMEM prefetch (wave-private) survives the
//      barrier instead of being drained by the compiler's vmcnt(0).
//  (b) P-tile pipeline: MFMA consumes P(jt) computed LAST iteration (pbuf
//      dbuf per wave), while VALU computes P(jt+1) and adj(jt+2) is issued.
//      -> adj latency covered by ~a full iteration; the old explicit
//      lgkmcnt(0)-before-MFMA stall is gone (barrier already drained it).
//  (c) single adj register set (consume-then-refill) -- no spill (round-2
//      lesson: 2 live sets => scratch, WRITE_SIZE 37->395 MB).
// Issue order matters: hreg (hT) loads issued BEFORE adj refill, so the
// hbuf-commit's dependency wait is a counted vmcnt that leaves adj in flight.
__global__ __launch_bounds__(256, 3) void k_flash(const float* __restrict__ adj,
                                                  const _Float16* __restrict__ hT,
                                                  const float* __restrict__ s1,
                                                  const float* __restrict__ s2,
                                                  const float* __restrict__ s2max,
                                                  float* __restrict__ part_acc,
                                                  float* __restrict__ part_l) {
    __shared__ _Float16 hbuf[2][128 * 64];    // 32 KB, hT dbuf, xor-swizzled
    __shared__ _Float16 pbuf[4][2][16 * 64];  // 16 KB, wave-private P dbuf

    const int t    = threadIdx.x;
    const int bid  = blockIdx.x;
    const int sp   = bid & 3;                 // j-split
    const int rb   = (bid >> 2) & 63;         // 64-row block within batch
    const int b    = bid >> 8;                // batch
    const int w    = t >> 6, lane = t & 63;
    const int quad = lane >> 4, ln15 = lane & 15;
    const int g    = quad;                    // row-group for p-compute
    const int cl   = ln15;                    // col-lane for p-compute
    const int rowb = rb * 64 + w * 16;        // wave's 16-row base
    const float*    adj_w = adj + (size_t)b * 4096 * 4096 + (size_t)rowb * 4096;
    const _Float16* hT_b  = hT + (size_t)b * 128 * 4096;
    const float*    s2_b  = s2 + b * 4096;
    const float     s2m   = s2max[b];
    const int jwbase = sp * 1024;

    float s1r[4], mh[4];
    #pragma unroll
    for (int L = 0; L < 4; ++L) {
        s1r[L] = s1[b * 4096 + rowb + L * 4 + g];
        mh[L]  = fmaxf(0.f, s1r[L] + s2m);
    }

    // hT staging geometry: thread covers f-rows i*32+(t>>3), j-chunk t&7
    const int sf  = t >> 3;
    const int sc  = t & 7;
    const int fb7 = ln15 & 7;

    float4_t acc[8] = {};
    float4_t psacc = {0.f, 0.f, 0.f, 0.f};
    float4_t av[4];
    float4_t s2v;

    // p-compute: consume av/s2v -> P into pbuf[w][slot], accumulate psacc
    auto pcompute = [&](int slot) {
        #pragma unroll
        for (int L = 0; L < 4; ++L) {
            half4_t qv;
            #pragma unroll
            for (int c = 0; c < 4; ++c) {
                float x = s1r[L] + s2v[c];
                float e = x > 0.f ? x : 0.2f * x;
                float p = av[L][c] > 0.f ? __expf(fmaf(av[L][c], e, -mh[L])) : 0.f;
                _Float16 q = (_Float16)p;
                qv[c] = q;
                psacc[L] += (float)q;
            }
            const int r     = L * 4 + g;
            const int c0    = cl * 4;
            const int chunk = (c0 >> 3) ^ (r & 7);
            *(half4_t*)&pbuf[w][slot][r * 64 + chunk * 8 + (c0 & 7)] = qv;
        }
    };

    // ---- prologue ----
    {
        // 1) issue hT tile-0 loads (oldest VMEM)
        half8 hreg[4];
        #pragma unroll
        for (int i = 0; i < 4; ++i) {
            int f = i * 32 + sf;
            hreg[i] = *(const half8*)&hT_b[(size_t)f * 4096 + jwbase + sc * 8];
        }
        // 2) issue adj(0)/s2(0)
        #pragma unroll
        for (int L = 0; L < 4; ++L)
            av[L] = *(const float4_t*)&adj_w[(size_t)(L * 4 + g) * 4096 + jwbase + cl * 4];
        s2v = *(const float4_t*)&s2_b[jwbase + cl * 4];
        // 3) commit hT tile 0 (waits hreg only - counted)
        #pragma unroll
        for (int i = 0; i < 4; ++i) {
            int f = i * 32 + sf;
            *(half8*)&hbuf[0][f * 64 + ((sc ^ (f & 7)) << 3)] = hreg[i];
        }
        // 4) P(0) -> pbuf slot 0
        pcompute(0);
        // 5) issue adj(1)/s2(1) -- stays in flight across the barrier
        #pragma unroll
        for (int L = 0; L < 4; ++L)
            av[L] = *(const float4_t*)&adj_w[(size_t)(L * 4 + g) * 4096 + jwbase + 64 + cl * 4];
        s2v = *(const float4_t*)&s2_b[jwbase + 64 + cl * 4];
    }
    asm volatile("s_waitcnt lgkmcnt(0)" ::: "memory");
    __builtin_amdgcn_s_barrier();

    #pragma unroll 1
    for (int jt = 0; jt < 16; ++jt) {
        const int cur = jt & 1;
        const int j0  = jwbase + jt * 64;
        // ---- issue hT tile jt+1 loads FIRST (so later waits are counted) ----
        half8 hreg[4];
        const bool tail = (jt == 15);
        if (!tail) {
            #pragma unroll
            for (int i = 0; i < 4; ++i) {
                int f = i * 32 + sf;
                hreg[i] = *(const half8*)&hT_b[(size_t)f * 4096 + j0 + 64 + sc * 8];
            }
        }
        // ---- MFMA: A-frags from pbuf[w][cur] (written last iter), B hbuf[cur]
        half8 afrag[2];
        #pragma unroll
        for (int kc = 0; kc < 2; ++kc) {
            const int chunk = ((kc << 2) + quad) ^ (ln15 & 7);
            afrag[kc] = *(const half8*)&pbuf[w][cur][ln15 * 64 + chunk * 8];
        }
        #pragma unroll
        for (int nt = 0; nt < 8; ++nt) {
            #pragma unroll
            for (int kc = 0; kc < 2; ++kc) {
                const int fb = nt * 16 + ln15;
                half8 bfrag = *(const half8*)&hbuf[cur][fb * 64 + ((((kc << 2) + quad) ^ fb7) << 3)];
                acc[nt] = __builtin_amdgcn_mfma_f32_16x16x32_f16(afrag[kc], bfrag, acc[nt], 0, 0, 0);
            }
        }
        // ---- P(jt+1): consume av/s2v (loaded last iter), overlap with MFMA --
        if (!tail) pcompute(cur ^ 1);
        // ---- refill adj(jt+2)/s2(jt+2) -- in flight across next barrier ----
        if (jt < 14) {
            #pragma unroll
            for (int L = 0; L < 4; ++L)
                av[L] = *(const float4_t*)&adj_w[(size_t)(L * 4 + g) * 4096 + j0 + 128 + cl * 4];
            s2v = *(const float4_t*)&s2_b[j0 + 128 + cl * 4];
        }
        // ---- commit hT tile jt+1 (dep-wait: counted vmcnt, adj stays live) --
        if (!tail) {
            #pragma unroll
            for (int i = 0; i < 4; ++i) {
                int f = i * 32 + sf;
                *(half8*)&hbuf[cur ^ 1][f * 64 + ((sc ^ (f & 7)) << 3)] = hreg[i];
            }
            // raw barrier: order LDS only; VMEM (adj) NOT drained
            asm volatile("s_waitcnt lgkmcnt(0)" ::: "memory");
            __builtin_amdgcn_s_barrier();
        }
    }

    // ---- epilogue: reduce l within each 16-lane group, write partials ----
    #pragma unroll
    for (int o = 1; o < 16; o <<= 1) {
        #pragma unroll
        for (int L = 0; L < 4; ++L) psacc[L] += __shfl_xor(psacc[L], o);
    }
    const size_t growb = (size_t)b * 4096 + rowb;
    if (cl == 0) {
        #pragma unroll
        for (int L = 0; L < 4; ++L)
            part_l[(size_t)sp * 16384 + growb + L * 4 + g] = psacc[L];
    }
    float* pacc = part_acc + (size_t)sp * 16384 * 128;
    #pragma unroll
    for (int nt = 0; nt < 8; ++nt) {
        #pragma unroll
        for (int reg = 0; reg < 4; ++reg) {
            pacc[(growb + quad * 4 + reg) * 128 + nt * 16 + ln15] = acc[nt][reg];
        }
    }
}

// ---------------- Kernel E: sum 4 j-split partials, normalize, elu -----------
__global__ __launch_bounds__(256) void k_combine(const float* __restrict__ part_acc,
                                                 const float* __restrict__ part_l,
                                                 float* __restrict__ out) {
    const int idx = blockIdx.x * 256 + threadIdx.x;   // 0..524287
    const int e0  = idx * 4;
    const int gr  = e0 >> 7;
    float l = part_l[gr] + part_l[16384 + gr] + part_l[32768 + gr] + part_l[49152 + gr];
    float4_t a0 = *(const float4_t*)&part_acc[e0];
    float4_t a1 = *(const float4_t*)&part_acc[2097152 + e0];
    float4_t a2 = *(const float4_t*)&part_acc[4194304 + e0];
    float4_t a3 = *(const float4_t*)&part_acc[6291456 + e0];
    float4_t s  = (a0 + a1) + (a2 + a3);
    float rl = 1.f / l;
    float4_t o;
    #pragma unroll
    for (int c = 0; c < 4; ++c) {
        float v = s[c] * rl;
        o[c] = v > 0.f ? v : expm1f(v);
    }
    *(float4_t*)&((float*)out)[e0] = o;
}

extern "C" void kernel_launch(void* const* d_in, const int* in_sizes, int n_in,
                              void* d_out, int out_size, void* d_ws, size_t ws_size,
                              hipStream_t stream) {
    const float* inp = (const float*)d_in[0];   // (4,4096,256)
    const float* adj = (const float*)d_in[1];   // (4,4096,4096)
    const float* W   = (const float*)d_in[2];   // (256,128)
    const float* a   = (const float*)d_in[3];   // (256,1)
    float* out = (float*)d_out;                 // (4,4096,128)

    char* wsb = (char*)d_ws;
    _Float16* hT       = (_Float16*)(wsb);                // 4 MB
    float*    s1       = (float*)(wsb + 4194304);         // 64 KB
    float*    s2       = (float*)(wsb + 4259840);         // 64 KB
    float*    s2max    = (float*)(wsb + 4325376);         // 256 B
    float*    part_l   = (float*)(wsb + 4325632);         // 256 KB
    float*    part_acc = (float*)(wsb + 4587776);         // 32 MB (total ~36.4 MB)

    hipLaunchKernelGGL(k_prep,    dim3(512),  dim3(256), 0, stream, inp, W, a, s1, s2, hT);
    hipLaunchKernelGGL(k_s2max,   dim3(4),    dim3(256), 0, stream, s2, s2max);
    hipLaunchKernelGGL(k_flash,   dim3(1024), dim3(256), 0, stream, adj, hT, s1, s2, s2max,
                       part_acc, part_l);
    hipLaunchKernelGGL(k_combine, dim3(2048), dim3(256), 0, stream, part_acc, part_l, out);
}